// Round 6
// baseline (267.370 us; speedup 1.0000x reference)
//
#include <hip/hip_runtime.h>
#include <math.h>

// ---------------------------------------------------------------------------
// Attn_14920716386547 R6.
// R5: 219.7 us. attn FETCH 124->12 MB (XCD pin works) but occupancy 12.4%
// (2 blk/CU, unbalanced). GEMMs ~125 us without the m97 async-staging lever.
// Changes:
//  * GEMMs: m97 structure - unpadded LDS (stride 64), global_load_lds w=16
//    for A always (fp16 src) and for B on the big-ws path (pre-converted W).
//  * attn: 128-thread blocks (2 waves x 32 q-rows), LDS 52 KB -> 3 blk/CU,
//    1024 blocks heavy-first -> backfill load balance. Same verified math.
// ws (halves): Vth [0,4M) | Xh/Og overlay [4M,8M) | Wqkvh [8M,11M) |
//   Woh [11M,12M) (big path only). d_out: Qh|Kh scratch.
// ---------------------------------------------------------------------------

typedef _Float16 f16x8 __attribute__((ext_vector_type(8)));
typedef _Float16 f16x4 __attribute__((ext_vector_type(4)));
typedef _Float16 f16x2 __attribute__((ext_vector_type(2)));
typedef __attribute__((ext_vector_type(4))) float f32x4;
typedef __attribute__((ext_vector_type(16))) float f32x16;

#define MFMA16(a, b, c) __builtin_amdgcn_mfma_f32_16x16x32_f16(a, b, c, 0, 0, 0)
#define MFMA32(a, b, c) __builtin_amdgcn_mfma_f32_32x32x16_f16(a, b, c, 0, 0, 0)
#define QSCALE 0.18033688f /* 0.125 * log2(e): attention runs in exp2 domain */

__device__ __forceinline__ void async16(const void* g, void* l) {
  // async global->LDS, 16 B/lane; l must be the wave-uniform base (m104/m108)
  __builtin_amdgcn_global_load_lds(
      (const __attribute__((address_space(1))) unsigned int*)g,
      (__attribute__((address_space(3))) unsigned int*)l, 16, 0, 0);
}

__device__ __forceinline__ f16x2 pk2(float x, float y) {
  return __builtin_bit_cast(f16x2, __builtin_amdgcn_cvt_pkrtz(x, y));
}

__device__ __forceinline__ f16x8 cvt8(const float* __restrict__ p) {
  float4 a = *(const float4*)p;
  float4 b = *(const float4*)(p + 4);
  f16x2 p0 = pk2(a.x, a.y), p1 = pk2(a.z, a.w);
  f16x2 p2 = pk2(b.x, b.y), p3 = pk2(b.z, b.w);
  f16x8 h;
  h[0] = p0[0]; h[1] = p0[1]; h[2] = p1[0]; h[3] = p1[1];
  h[4] = p2[0]; h[5] = p2[1]; h[6] = p3[0]; h[7] = p3[1];
  return h;
}

// ---- fp32 -> fp16 convert: X always; with grid=4096 also Wq|Wk|Wv|Wo ------
__global__ void convert_all(const float* __restrict__ X, const float* __restrict__ Wq,
                            const float* __restrict__ Wk, const float* __restrict__ Wv,
                            const float* __restrict__ Wo, _Float16* __restrict__ Xh,
                            _Float16* __restrict__ Wqkvh, _Float16* __restrict__ Woh) {
  size_t i = ((size_t)blockIdx.x * 256 + threadIdx.x) * 8;
  const float* src; _Float16* dst; size_t off;
  if (i < 4194304u)      { src = X;  dst = Xh;              off = i; }
  else if (i < 5242880u) { src = Wq; dst = Wqkvh;           off = i - 4194304u; }
  else if (i < 6291456u) { src = Wk; dst = Wqkvh + 1048576; off = i - 5242880u; }
  else if (i < 7340032u) { src = Wv; dst = Wqkvh + 2097152; off = i - 6291456u; }
  else                   { src = Wo; dst = Woh;             off = i - 7340032u; }
  *(f16x8*)(dst + off) = cvt8(src + off);
}

// ---- QKV GEMM: C[4096,3072] = Xh @ W^T. m97-style async staging. ----------
template <int BH>
__global__ __launch_bounds__(256) void gemm_qkv(
    const _Float16* __restrict__ Xh, const float* __restrict__ Wq,
    const float* __restrict__ Wk, const float* __restrict__ Wv,
    const _Float16* __restrict__ Wh, _Float16* __restrict__ Qh,
    _Float16* __restrict__ Kh, _Float16* __restrict__ Vth) {
  __shared__ _Float16 As[128 * 64];   // unpadded: required by global_load_lds
  __shared__ _Float16 Bs[128 * 64];
  const int tid = threadIdx.x;
  const int wave = tid >> 6, lane = tid & 63;
  const int quad = lane >> 4, l16 = lane & 15;
  const int wm = (wave >> 1) * 64, wn = (wave & 1) * 64;
  const int bn = blockIdx.x, bm = blockIdx.y;    // XCD = bn%8
  const int mat = bn >> 3;                       // 0=Q 1=K 2=V (block-uniform)
  const float* Bsrc = (mat == 0) ? Wq : (mat == 1) ? Wk : Wv;
  const int brow0 = (bn & 7) * 128;

  f32x4 acc[4][4] = {};

  for (int k0 = 0; k0 < 1024; k0 += 64) {
    __syncthreads();
#pragma unroll
    for (int j = 0; j < 4; ++j) {                // A: 1024 x 16B chunks
      int chunk = j * 256 + tid;
      int row = chunk >> 3, c8 = chunk & 7;
      async16(&Xh[(size_t)(bm * 128 + row) * 1024 + k0 + c8 * 8],
              &As[(j * 256 + wave * 64) * 8]);
    }
#pragma unroll
    for (int j = 0; j < 4; ++j) {                // B: 1024 x 16B chunks
      int chunk = j * 256 + tid;
      int row = chunk >> 3, c8 = chunk & 7;
      if (BH)
        async16(&Wh[(size_t)(bn * 128 + row) * 1024 + k0 + c8 * 8],
                &Bs[(j * 256 + wave * 64) * 8]);
      else
        *(f16x8*)&Bs[chunk * 8] =
            cvt8(&Bsrc[(size_t)(brow0 + row) * 1024 + k0 + c8 * 8]);
    }
    __syncthreads();
#pragma unroll
    for (int kc = 0; kc < 2; ++kc) {
      f16x8 af[4], bf[4];
#pragma unroll
      for (int t = 0; t < 4; ++t) {
        af[t] = *(const f16x8*)&As[(wm + t * 16 + l16) * 64 + kc * 32 + quad * 8];
        bf[t] = *(const f16x8*)&Bs[(wn + t * 16 + l16) * 64 + kc * 32 + quad * 8];
      }
#pragma unroll
      for (int mt = 0; mt < 4; ++mt)
#pragma unroll
        for (int nt = 0; nt < 4; ++nt)
          acc[mt][nt] = MFMA16(af[mt], bf[nt], acc[mt][nt]);
    }
  }

  // C-layout: col = l16, row = quad*4 + r  [verified m89/m91]
#pragma unroll
  for (int mt = 0; mt < 4; ++mt) {
    int m_base = bm * 128 + wm + mt * 16 + quad * 4;
    int b = m_base >> 11, sb = m_base & 2047;
#pragma unroll
    for (int nt = 0; nt < 4; ++nt) {
      int ob = (bn * 128 + wn + nt * 16) & 1023;
      int h = ob >> 6;
      int dh = (ob & 63) + l16;
      size_t bh = (size_t)(b * 16 + h);
      if (mat == 0) {
#pragma unroll
        for (int r = 0; r < 4; ++r)
          Qh[(bh * 2048 + sb + r) * 64 + dh] = (_Float16)(acc[mt][nt][r] * QSCALE);
      } else if (mat == 1) {
#pragma unroll
        for (int r = 0; r < 4; ++r)
          Kh[(bh * 2048 + sb + r) * 64 + dh] = (_Float16)acc[mt][nt][r];
      } else {
        f16x4 pk;
        pk[0] = (_Float16)acc[mt][nt][0];
        pk[1] = (_Float16)acc[mt][nt][1];
        pk[2] = (_Float16)acc[mt][nt][2];
        pk[3] = (_Float16)acc[mt][nt][3];
        *(f16x4*)&Vth[(bh * 64 + dh) * 2048 + sb] = pk;
      }
    }
  }
}

// ---- attention: 2 waves x 32 q-rows (64 q-rows/block), KT=128 -------------
// grid.x = bh (XCD-pinned), grid.y: qt = 31-y (heavy first, backfill balance)
__global__ __launch_bounds__(128) void attn_kernel(
    const _Float16* __restrict__ Qg, const _Float16* __restrict__ Kg,
    const _Float16* __restrict__ Vtg, _Float16* __restrict__ Og) {
  __shared__ _Float16 Kl[128 * 72];        // [key][dh]   18.4 KB
  __shared__ _Float16 Vl[64 * 136];        // [dh][key]   17.4 KB
  __shared__ _Float16 Pl[2 * 32 * 136];    // per-wave P  17.4 KB (52 KB tot)
  const int bh = blockIdx.x;               // XCD = bh % 8
  const int qt = 31 - (int)blockIdx.y;     // heavy tiles dispatched first
  const int q0 = qt * 64;
  const int tid = threadIdx.x;
  const int wave = tid >> 6, lane = tid & 63;
  const int l31 = lane & 31, hl = lane >> 5;
  const int b = bh >> 4, h = bh & 15;
  _Float16* myP = &Pl[wave * 32 * 136];

  // Q A-frags (32x32x16: m = l31, k = 16t + 8*hl + j)
  const _Float16* Qbase =
      Qg + ((size_t)bh * 2048 + q0 + wave * 32 + l31) * 64 + hl * 8;
  f16x8 aq[4];
#pragma unroll
  for (int t = 0; t < 4; ++t) aq[t] = *(const f16x8*)(Qbase + 16 * t);

  f32x16 oacc[2] = {};
  float lsum[16] = {};

  const int ktiles = (q0 + 191) >> 7;      // 128-key tiles covering [0,q0+64)
  for (int kt = 0; kt < ktiles; ++kt) {
    const int k0 = kt << 7;
    __syncthreads();
#pragma unroll
    for (int i = tid; i < 1024; i += 128) {     // K tile: 128 keys x 64 dh
      int row = i >> 3, c8 = i & 7;
      *(int4*)&Kl[row * 72 + c8 * 8] =
          *(const int4*)&Kg[((size_t)bh * 2048 + k0 + row) * 64 + c8 * 8];
    }
#pragma unroll
    for (int i = tid; i < 1024; i += 128) {     // V^T tile: 64 dh x 128 keys
      int row = i >> 4, c16 = i & 15;
      *(int4*)&Vl[row * 136 + c16 * 8] =
          *(const int4*)&Vtg[((size_t)bh * 64 + row) * 2048 + k0 + c16 * 8];
    }
    __syncthreads();

    const bool diag = (kt == ktiles - 1);

    // S = Q K^T per 32-key subtile; exp2; P to LDS (C-layout -> [row][key])
#pragma unroll
    for (int s32t = 0; s32t < 4; ++s32t) {
      f32x16 sv = {};
#pragma unroll
      for (int t = 0; t < 4; ++t) {
        f16x8 kb = *(const f16x8*)&Kl[(s32t * 32 + l31) * 72 + t * 16 + hl * 8];
        sv = MFMA32(aq[t], kb, sv);
      }
#pragma unroll
      for (int r = 0; r < 16; ++r) {
        float x = sv[r];
        int rowloc = wave * 32 + (r & 3) + 8 * (r >> 2) + 4 * hl;
        // global causal mask (q0 and k0 origins differ for odd qt)
        if (diag && (k0 + s32t * 32 + l31 > q0 + rowloc)) x = -1e30f;
        x = __builtin_amdgcn_exp2f(x);
        lsum[r] += x;
        myP[((r & 3) + 8 * (r >> 2) + 4 * hl) * 136 + s32t * 32 + l31] =
            (_Float16)x;
      }
    }

    // P A-frags (same-wave LDS RAW; compiler inserts lgkmcnt wait)
    f16x8 ap[8];
#pragma unroll
    for (int t = 0; t < 8; ++t)
      ap[t] = *(const f16x8*)&myP[l31 * 136 + t * 16 + hl * 8];

    // O += P V  (16 MFMA32)
#pragma unroll
    for (int d = 0; d < 2; ++d)
#pragma unroll
      for (int t = 0; t < 8; ++t) {
        f16x8 vb = *(const f16x8*)&Vl[(d * 32 + l31) * 136 + t * 16 + hl * 8];
        oacc[d] = MFMA32(ap[t], vb, oacc[d]);
      }
  }

  // reduce lsum over the 32 lanes sharing each row (xor<32 stays in half)
#pragma unroll
  for (int r = 0; r < 16; ++r) {
    float v = lsum[r];
#pragma unroll
    for (int off = 1; off < 32; off <<= 1) v += __shfl_xor(v, off);
    lsum[r] = v;
  }
#pragma unroll
  for (int d = 0; d < 2; ++d)
#pragma unroll
    for (int r = 0; r < 16; ++r) {
      int srow = q0 + wave * 32 + (r & 3) + 8 * (r >> 2) + 4 * hl;
      int dh = d * 32 + l31;
      Og[(((size_t)b * 2048 + srow) * 16 + h) * 64 + dh] =
          (_Float16)(oacc[d][r] / lsum[r]);
    }
}

// ---- output GEMM: out = Og(f16) @ Wo^T. m97-style async staging. ----------
template <int BH>
__global__ __launch_bounds__(256) void gemm_out(
    const _Float16* __restrict__ A, const float* __restrict__ Wo,
    const _Float16* __restrict__ Woh, float* __restrict__ Co) {
  __shared__ _Float16 As[128 * 64];
  __shared__ _Float16 Bs[128 * 64];
  const int tid = threadIdx.x;
  const int wave = tid >> 6, lane = tid & 63;
  const int quad = lane >> 4, l16 = lane & 15;
  const int wm = (wave >> 1) * 64, wn = (wave & 1) * 64;
  const int bn = blockIdx.x, bm = blockIdx.y;   // XCD = bn%8

  f32x4 acc[4][4] = {};

  for (int k0 = 0; k0 < 1024; k0 += 64) {
    __syncthreads();
#pragma unroll
    for (int j = 0; j < 4; ++j) {
      int chunk = j * 256 + tid;
      int row = chunk >> 3, c8 = chunk & 7;
      async16(&A[(size_t)(bm * 128 + row) * 1024 + k0 + c8 * 8],
              &As[(j * 256 + wave * 64) * 8]);
    }
#pragma unroll
    for (int j = 0; j < 4; ++j) {
      int chunk = j * 256 + tid;
      int row = chunk >> 3, c8 = chunk & 7;
      if (BH)
        async16(&Woh[(size_t)(bn * 128 + row) * 1024 + k0 + c8 * 8],
                &Bs[(j * 256 + wave * 64) * 8]);
      else
        *(f16x8*)&Bs[chunk * 8] =
            cvt8(&Wo[(size_t)(bn * 128 + row) * 1024 + k0 + c8 * 8]);
    }
    __syncthreads();
#pragma unroll
    for (int kc = 0; kc < 2; ++kc) {
      f16x8 af[4], bf[4];
#pragma unroll
      for (int t = 0; t < 4; ++t) {
        af[t] = *(const f16x8*)&As[(wm + t * 16 + l16) * 64 + kc * 32 + quad * 8];
        bf[t] = *(const f16x8*)&Bs[(wn + t * 16 + l16) * 64 + kc * 32 + quad * 8];
      }
#pragma unroll
      for (int mt = 0; mt < 4; ++mt)
#pragma unroll
        for (int nt = 0; nt < 4; ++nt)
          acc[mt][nt] = MFMA16(af[mt], bf[nt], acc[mt][nt]);
    }
  }

#pragma unroll
  for (int mt = 0; mt < 4; ++mt) {
    int m_base = bm * 128 + wm + mt * 16 + quad * 4;
#pragma unroll
    for (int nt = 0; nt < 4; ++nt) {
      int n = bn * 128 + wn + nt * 16 + l16;
#pragma unroll
      for (int r = 0; r < 4; ++r)
        Co[(size_t)(m_base + r) * 1024 + n] = acc[mt][nt][r];
    }
  }
}

extern "C" void kernel_launch(void* const* d_in, const int* in_sizes, int n_in,
                              void* d_out, int out_size, void* d_ws, size_t ws_size,
                              hipStream_t stream) {
  const float* X  = (const float*)d_in[0];
  const float* Wq = (const float*)d_in[1];
  const float* Wk = (const float*)d_in[2];
  const float* Wv = (const float*)d_in[3];
  const float* Wo = (const float*)d_in[4];
  float* out = (float*)d_out;

  _Float16* Qh    = (_Float16*)d_out;        // 4M halves (d_out scratch)
  _Float16* Kh    = Qh + 4194304;            // 4M halves
  _Float16* Vth   = (_Float16*)d_ws;         // 4M halves [b,h,dh,s]
  _Float16* Xh    = Vth + 4194304;           // 4M halves (Og overlay)
  _Float16* Og    = Xh;
  _Float16* Wqkvh = Xh + 4194304;            // 3M halves (big path only)
  _Float16* Woh   = Wqkvh + 3145728;         // 1M halves

  const bool big = (ws_size >= 25165824u);

  convert_all<<<big ? 4096 : 2048, 256, 0, stream>>>(X, Wq, Wk, Wv, Wo,
                                                     Xh, Wqkvh, Woh);
  if (big)
    gemm_qkv<1><<<dim3(24, 32), 256, 0, stream>>>(Xh, Wq, Wk, Wv, Wqkvh,
                                                  Qh, Kh, Vth);
  else
    gemm_qkv<0><<<dim3(24, 32), 256, 0, stream>>>(Xh, Wq, Wk, Wv, nullptr,
                                                  Qh, Kh, Vth);
  attn_kernel<<<dim3(32, 32), 128, 0, stream>>>(Qh, Kh, Vth, Og);
  if (big)
    gemm_out<1><<<dim3(8, 32), 256, 0, stream>>>(Og, Wo, Woh, out);
  else
    gemm_out<0><<<dim3(8, 32), 256, 0, stream>>>(Og, Wo, nullptr, out);
}

// Round 7
// 218.245 us; speedup vs baseline: 1.2251x; 1.2251x over previous
//
#include <hip/hip_runtime.h>
#include <math.h>

// ---------------------------------------------------------------------------
// Attn_14920716386547 R7 = R5 (219.7 us) + split-P attn for 3 blocks/CU.
// R6 post-mortem: 64-row attn blocks doubled staging work and cut waves/CU
// (110.8 us); async16 GEMMs regressed ~15 us -> both reverted to R5.
// R7 change (attn only): P streams through LDS in two 64-key halves ->
// Pl 34.8 KB -> 18.4 KB, total LDS 70.7 -> 54.3 KB -> 3 blocks/CU (was 2),
// 512 heavy-first blocks now have real backfill -> makespan ~16 iters not 32.
// ws (halves): Vth [0,4M) | Xh/Og overlay [4M,8M) | Wqkvh [8M,11M) |
//   Woh [11M,12M) (big path only). d_out: Qh|Kh scratch (dead before out).
// ---------------------------------------------------------------------------

typedef _Float16 f16x8 __attribute__((ext_vector_type(8)));
typedef _Float16 f16x4 __attribute__((ext_vector_type(4)));
typedef _Float16 f16x2 __attribute__((ext_vector_type(2)));
typedef __attribute__((ext_vector_type(4))) float f32x4;
typedef __attribute__((ext_vector_type(16))) float f32x16;

#define MFMA16(a, b, c) __builtin_amdgcn_mfma_f32_16x16x32_f16(a, b, c, 0, 0, 0)
#define MFMA32(a, b, c) __builtin_amdgcn_mfma_f32_32x32x16_f16(a, b, c, 0, 0, 0)
#define QSCALE 0.18033688f /* 0.125 * log2(e): attention runs in exp2 domain */

__device__ __forceinline__ f16x2 pk2(float x, float y) {
  return __builtin_bit_cast(f16x2, __builtin_amdgcn_cvt_pkrtz(x, y));
}

__device__ __forceinline__ f16x8 cvt8(const float* __restrict__ p) {
  float4 a = *(const float4*)p;
  float4 b = *(const float4*)(p + 4);
  f16x2 p0 = pk2(a.x, a.y), p1 = pk2(a.z, a.w);
  f16x2 p2 = pk2(b.x, b.y), p3 = pk2(b.z, b.w);
  f16x8 h;
  h[0] = p0[0]; h[1] = p0[1]; h[2] = p1[0]; h[3] = p1[1];
  h[4] = p2[0]; h[5] = p2[1]; h[6] = p3[0]; h[7] = p3[1];
  return h;
}

// ---- fp32 -> fp16 convert: X always; with grid=4096 also Wq|Wk|Wv|Wo ------
__global__ void convert_all(const float* __restrict__ X, const float* __restrict__ Wq,
                            const float* __restrict__ Wk, const float* __restrict__ Wv,
                            const float* __restrict__ Wo, _Float16* __restrict__ Xh,
                            _Float16* __restrict__ Wqkvh, _Float16* __restrict__ Woh) {
  size_t i = ((size_t)blockIdx.x * 256 + threadIdx.x) * 8;
  const float* src; _Float16* dst; size_t off;
  if (i < 4194304u)      { src = X;  dst = Xh;              off = i; }
  else if (i < 5242880u) { src = Wq; dst = Wqkvh;           off = i - 4194304u; }
  else if (i < 6291456u) { src = Wk; dst = Wqkvh + 1048576; off = i - 5242880u; }
  else if (i < 7340032u) { src = Wv; dst = Wqkvh + 2097152; off = i - 6291456u; }
  else                   { src = Wo; dst = Woh;             off = i - 7340032u; }
  *(f16x8*)(dst + off) = cvt8(src + off);
}

// ---- QKV GEMM: C[4096,3072] = Xh @ W^T. BH=1: W pre-converted fp16 --------
template <int BH>
__global__ __launch_bounds__(256) void gemm_qkv(
    const _Float16* __restrict__ Xh, const float* __restrict__ Wq,
    const float* __restrict__ Wk, const float* __restrict__ Wv,
    const _Float16* __restrict__ Wh, _Float16* __restrict__ Qh,
    _Float16* __restrict__ Kh, _Float16* __restrict__ Vth) {
  __shared__ _Float16 As[128 * 72];
  __shared__ _Float16 Bs[128 * 72];
  const int tid = threadIdx.x;
  const int wave = tid >> 6, lane = tid & 63;
  const int quad = lane >> 4, l16 = lane & 15;
  const int wm = (wave >> 1) * 64, wn = (wave & 1) * 64;
  const int bn = blockIdx.x, bm = blockIdx.y;    // XCD = bn%8: W slice per XCD
  const int mat = bn >> 3;                       // 0=Q 1=K 2=V (block-uniform)
  const float* Bsrc = (mat == 0) ? Wq : (mat == 1) ? Wk : Wv;
  const int brow0 = (bn & 7) * 128;

  f32x4 acc[4][4] = {};

  for (int k0 = 0; k0 < 1024; k0 += 64) {
    __syncthreads();
#pragma unroll
    for (int j = 0; j < 4; ++j) {
      int idx = tid + j * 256;                   // 1024 chunks of 8 = 128x64
      int row = idx >> 3, c8 = idx & 7;
      *(int4*)&As[row * 72 + c8 * 8] =
          *(const int4*)&Xh[(size_t)(bm * 128 + row) * 1024 + k0 + c8 * 8];
      if (BH)
        *(int4*)&Bs[row * 72 + c8 * 8] =
            *(const int4*)&Wh[(size_t)(bn * 128 + row) * 1024 + k0 + c8 * 8];
      else
        *(f16x8*)&Bs[row * 72 + c8 * 8] =
            cvt8(&Bsrc[(size_t)(brow0 + row) * 1024 + k0 + c8 * 8]);
    }
    __syncthreads();
#pragma unroll
    for (int kc = 0; kc < 2; ++kc) {
      f16x8 af[4], bf[4];
#pragma unroll
      for (int t = 0; t < 4; ++t) {
        af[t] = *(const f16x8*)&As[(wm + t * 16 + l16) * 72 + kc * 32 + quad * 8];
        bf[t] = *(const f16x8*)&Bs[(wn + t * 16 + l16) * 72 + kc * 32 + quad * 8];
      }
#pragma unroll
      for (int mt = 0; mt < 4; ++mt)
#pragma unroll
        for (int nt = 0; nt < 4; ++nt)
          acc[mt][nt] = MFMA16(af[mt], bf[nt], acc[mt][nt]);
    }
  }

  // C-layout: col = l16, row = quad*4 + r  [verified m89/m91]
#pragma unroll
  for (int mt = 0; mt < 4; ++mt) {
    int m_base = bm * 128 + wm + mt * 16 + quad * 4;
    int b = m_base >> 11, sb = m_base & 2047;
#pragma unroll
    for (int nt = 0; nt < 4; ++nt) {
      int ob = (bn * 128 + wn + nt * 16) & 1023; // col within this matrix
      int h = ob >> 6;
      int dh = (ob & 63) + l16;
      size_t bh = (size_t)(b * 16 + h);
      if (mat == 0) {
#pragma unroll
        for (int r = 0; r < 4; ++r)
          Qh[(bh * 2048 + sb + r) * 64 + dh] = (_Float16)(acc[mt][nt][r] * QSCALE);
      } else if (mat == 1) {
#pragma unroll
        for (int r = 0; r < 4; ++r)
          Kh[(bh * 2048 + sb + r) * 64 + dh] = (_Float16)acc[mt][nt][r];
      } else {
        f16x4 pk;
        pk[0] = (_Float16)acc[mt][nt][0];
        pk[1] = (_Float16)acc[mt][nt][1];
        pk[2] = (_Float16)acc[mt][nt][2];
        pk[3] = (_Float16)acc[mt][nt][3];
        *(f16x4*)&Vth[(bh * 64 + dh) * 2048 + sb] = pk;   // 8B aligned
      }
    }
  }
}

// ---- attention: 4 waves x 32 q-rows (128 q-rows/block), KT=128, split-P ---
// grid.x = bh (XCD-pinned), grid.y: qt = 15-y (heavy first, 3 blk/CU backfill)
__global__ __launch_bounds__(256) void attn_kernel(
    const _Float16* __restrict__ Qg, const _Float16* __restrict__ Kg,
    const _Float16* __restrict__ Vtg, _Float16* __restrict__ Og) {
  __shared__ _Float16 Kl[128 * 72];        // [key][dh]        18,432 B
  __shared__ _Float16 Vl[64 * 136];        // [dh][key]        17,408 B
  __shared__ _Float16 Pl[4 * 32 * 72];     // per-wave P half  18,432 B (54,272)
  const int bh = blockIdx.x;               // XCD = bh % 8
  const int qt = 15 - (int)blockIdx.y;     // heavy tiles dispatched first
  const int q0 = qt * 128;
  const int tid = threadIdx.x;
  const int wave = tid >> 6, lane = tid & 63;
  const int l31 = lane & 31, hl = lane >> 5;
  const int b = bh >> 4, h = bh & 15;
  _Float16* myP = &Pl[wave * 32 * 72];

  // Q A-frags (32x32x16: m = l31, k = 16t + 8*hl + j)
  const _Float16* Qbase =
      Qg + ((size_t)bh * 2048 + q0 + wave * 32 + l31) * 64 + hl * 8;
  f16x8 aq[4];
#pragma unroll
  for (int t = 0; t < 4; ++t) aq[t] = *(const f16x8*)(Qbase + 16 * t);

  f32x16 oacc[2] = {};
  float lsum[16] = {};

  const int ktiles = qt + 1;
  for (int kt = 0; kt < ktiles; ++kt) {
    const int k0 = kt << 7;
    __syncthreads();
#pragma unroll
    for (int i = tid; i < 1024; i += 256) {     // K tile: 128 keys x 64 dh
      int row = i >> 3, c8 = i & 7;
      *(int4*)&Kl[row * 72 + c8 * 8] =
          *(const int4*)&Kg[((size_t)bh * 2048 + k0 + row) * 64 + c8 * 8];
    }
#pragma unroll
    for (int i = tid; i < 1024; i += 256) {     // V^T tile: 64 dh x 128 keys
      int row = i >> 4, c16 = i & 15;
      *(int4*)&Vl[row * 136 + c16 * 8] =
          *(const int4*)&Vtg[((size_t)bh * 64 + row) * 2048 + k0 + c16 * 8];
    }
    __syncthreads();

    const bool diag = (kt == ktiles - 1);       // k0 == q0 on last tile

    // process keys in two 64-key halves through the small P buffer
#pragma unroll
    for (int half = 0; half < 2; ++half) {
#pragma unroll
      for (int s32t = 0; s32t < 2; ++s32t) {
        f32x16 sv = {};
#pragma unroll
        for (int t = 0; t < 4; ++t) {
          f16x8 kb = *(const f16x8*)
              &Kl[(half * 64 + s32t * 32 + l31) * 72 + t * 16 + hl * 8];
          sv = MFMA32(aq[t], kb, sv);
        }
#pragma unroll
        for (int r = 0; r < 16; ++r) {
          float x = sv[r];
          int rowin = (r & 3) + 8 * (r >> 2) + 4 * hl;        // row in wave
          if (diag && (half * 64 + s32t * 32 + l31 > wave * 32 + rowin))
            x = -1e30f;
          x = __builtin_amdgcn_exp2f(x);
          lsum[r] += x;
          myP[rowin * 72 + s32t * 32 + l31] = (_Float16)x;
        }
      }
      // P A-frags for this 64-key half (same-wave LDS RAW, compiler waits)
      f16x8 ap[4];
#pragma unroll
      for (int t = 0; t < 4; ++t)
        ap[t] = *(const f16x8*)&myP[l31 * 72 + t * 16 + hl * 8];
      // O += P V over this half (8 MFMA32)
#pragma unroll
      for (int d = 0; d < 2; ++d)
#pragma unroll
        for (int t = 0; t < 4; ++t) {
          f16x8 vb = *(const f16x8*)
              &Vl[(d * 32 + l31) * 136 + half * 64 + t * 16 + hl * 8];
          oacc[d] = MFMA32(ap[t], vb, oacc[d]);
        }
    }
  }

  // reduce lsum over the 32 lanes sharing each row (xor<32 stays in half)
#pragma unroll
  for (int r = 0; r < 16; ++r) {
    float v = lsum[r];
#pragma unroll
    for (int off = 1; off < 32; off <<= 1) v += __shfl_xor(v, off);
    lsum[r] = v;
  }
  // write O: [b,s,h,dh] fp16; C-layout row map as S  [m74/m101]
#pragma unroll
  for (int d = 0; d < 2; ++d)
#pragma unroll
    for (int r = 0; r < 16; ++r) {
      int srow = q0 + wave * 32 + (r & 3) + 8 * (r >> 2) + 4 * hl;
      int dh = d * 32 + l31;
      Og[(((size_t)b * 2048 + srow) * 16 + h) * 64 + dh] =
          (_Float16)(oacc[d][r] / lsum[r]);
    }
}

// ---- output GEMM: out = Og(f16) @ Wo^T. BH=1: Wo pre-converted ------------
template <int BH>
__global__ __launch_bounds__(256) void gemm_out(
    const _Float16* __restrict__ A, const float* __restrict__ Wo,
    const _Float16* __restrict__ Woh, float* __restrict__ Co) {
  __shared__ _Float16 As[128 * 72];
  __shared__ _Float16 Bs[128 * 72];
  const int tid = threadIdx.x;
  const int wave = tid >> 6, lane = tid & 63;
  const int quad = lane >> 4, l16 = lane & 15;
  const int wm = (wave >> 1) * 64, wn = (wave & 1) * 64;
  const int bn = blockIdx.x, bm = blockIdx.y;   // XCD = bn%8

  f32x4 acc[4][4] = {};

  for (int k0 = 0; k0 < 1024; k0 += 64) {
    __syncthreads();
#pragma unroll
    for (int j = 0; j < 4; ++j) {
      int idx = tid + j * 256;
      int row = idx >> 3, c8 = idx & 7;
      *(int4*)&As[row * 72 + c8 * 8] =
          *(const int4*)&A[(size_t)(bm * 128 + row) * 1024 + k0 + c8 * 8];
      if (BH)
        *(int4*)&Bs[row * 72 + c8 * 8] =
            *(const int4*)&Woh[(size_t)(bn * 128 + row) * 1024 + k0 + c8 * 8];
      else
        *(f16x8*)&Bs[row * 72 + c8 * 8] =
            cvt8(&Wo[(size_t)(bn * 128 + row) * 1024 + k0 + c8 * 8]);
    }
    __syncthreads();
#pragma unroll
    for (int kc = 0; kc < 2; ++kc) {
      f16x8 af[4], bf[4];
#pragma unroll
      for (int t = 0; t < 4; ++t) {
        af[t] = *(const f16x8*)&As[(wm + t * 16 + l16) * 72 + kc * 32 + quad * 8];
        bf[t] = *(const f16x8*)&Bs[(wn + t * 16 + l16) * 72 + kc * 32 + quad * 8];
      }
#pragma unroll
      for (int mt = 0; mt < 4; ++mt)
#pragma unroll
        for (int nt = 0; nt < 4; ++nt)
          acc[mt][nt] = MFMA16(af[mt], bf[nt], acc[mt][nt]);
    }
  }

#pragma unroll
  for (int mt = 0; mt < 4; ++mt) {
    int m_base = bm * 128 + wm + mt * 16 + quad * 4;
#pragma unroll
    for (int nt = 0; nt < 4; ++nt) {
      int n = bn * 128 + wn + nt * 16 + l16;
#pragma unroll
      for (int r = 0; r < 4; ++r)
        Co[(size_t)(m_base + r) * 1024 + n] = acc[mt][nt][r];
    }
  }
}

extern "C" void kernel_launch(void* const* d_in, const int* in_sizes, int n_in,
                              void* d_out, int out_size, void* d_ws, size_t ws_size,
                              hipStream_t stream) {
  const float* X  = (const float*)d_in[0];
  const float* Wq = (const float*)d_in[1];
  const float* Wk = (const float*)d_in[2];
  const float* Wv = (const float*)d_in[3];
  const float* Wo = (const float*)d_in[4];
  float* out = (float*)d_out;

  _Float16* Qh    = (_Float16*)d_out;        // 4M halves (d_out scratch)
  _Float16* Kh    = Qh + 4194304;            // 4M halves
  _Float16* Vth   = (_Float16*)d_ws;         // 4M halves [b,h,dh,s]
  _Float16* Xh    = Vth + 4194304;           // 4M halves (Og overlay)
  _Float16* Og    = Xh;
  _Float16* Wqkvh = Xh + 4194304;            // 3M halves (big path only)
  _Float16* Woh   = Wqkvh + 3145728;         // 1M halves

  const bool big = (ws_size >= 25165824u);

  convert_all<<<big ? 4096 : 2048, 256, 0, stream>>>(X, Wq, Wk, Wv, Wo,
                                                     Xh, Wqkvh, Woh);
  if (big)
    gemm_qkv<1><<<dim3(24, 32), 256, 0, stream>>>(Xh, Wq, Wk, Wv, Wqkvh,
                                                  Qh, Kh, Vth);
  else
    gemm_qkv<0><<<dim3(24, 32), 256, 0, stream>>>(Xh, Wq, Wk, Wv, nullptr,
                                                  Qh, Kh, Vth);
  attn_kernel<<<dim3(32, 16), 256, 0, stream>>>(Qh, Kh, Vth, Og);
  if (big)
    gemm_out<1><<<dim3(8, 32), 256, 0, stream>>>(Og, Wo, Woh, out);
  else
    gemm_out<0><<<dim3(8, 32), 256, 0, stream>>>(Og, Wo, nullptr, out);
}

// Round 8
// 212.499 us; speedup vs baseline: 1.2582x; 1.0270x over previous
//
#include <hip/hip_runtime.h>
#include <math.h>

// ---------------------------------------------------------------------------
// Attn_14920716386547 R8.
// R7: 218.2 us, attn 75.3 us latency-bound (2 blk/CU grid-limited; P LDS
// round-trip = 64 scalar ds_write_b16 + reads per iter on the critical path).
// Changes:
//  * attn: compute S^T = K*Q^T (operand swap, free). P now lives in registers
//    with col=qrow; PV B-frags built via 4 shfl_xor(32) + pack/cndmask per
//    32-key subtile. Pl deleted -> LDS 35.8 KB; lsum = 1 scalar/lane;
//    O written as f16x4. No LDS P traffic at all.
//  * gemm_out: 128x64 tiles -> 512 blocks = 2 blk/CU (was 1).
// ws (halves): Vth [0,4M) | Xh/Og overlay [4M,8M) | Wqkvh [8M,11M) |
//   Woh [11M,12M) (big path only). d_out: Qh|Kh scratch (dead before out).
// ---------------------------------------------------------------------------

typedef _Float16 f16x8 __attribute__((ext_vector_type(8)));
typedef _Float16 f16x4 __attribute__((ext_vector_type(4)));
typedef _Float16 f16x2 __attribute__((ext_vector_type(2)));
typedef __attribute__((ext_vector_type(4))) float f32x4;
typedef __attribute__((ext_vector_type(16))) float f32x16;

#define MFMA16(a, b, c) __builtin_amdgcn_mfma_f32_16x16x32_f16(a, b, c, 0, 0, 0)
#define MFMA32(a, b, c) __builtin_amdgcn_mfma_f32_32x32x16_f16(a, b, c, 0, 0, 0)
#define QSCALE 0.18033688f /* 0.125 * log2(e): attention runs in exp2 domain */

__device__ __forceinline__ f16x2 pk2(float x, float y) {
  return __builtin_bit_cast(f16x2, __builtin_amdgcn_cvt_pkrtz(x, y));
}

__device__ __forceinline__ f16x8 cvt8(const float* __restrict__ p) {
  float4 a = *(const float4*)p;
  float4 b = *(const float4*)(p + 4);
  f16x2 p0 = pk2(a.x, a.y), p1 = pk2(a.z, a.w);
  f16x2 p2 = pk2(b.x, b.y), p3 = pk2(b.z, b.w);
  f16x8 h;
  h[0] = p0[0]; h[1] = p0[1]; h[2] = p1[0]; h[3] = p1[1];
  h[4] = p2[0]; h[5] = p2[1]; h[6] = p3[0]; h[7] = p3[1];
  return h;
}

// ---- fp32 -> fp16 convert: X always; with grid=4096 also Wq|Wk|Wv|Wo ------
__global__ void convert_all(const float* __restrict__ X, const float* __restrict__ Wq,
                            const float* __restrict__ Wk, const float* __restrict__ Wv,
                            const float* __restrict__ Wo, _Float16* __restrict__ Xh,
                            _Float16* __restrict__ Wqkvh, _Float16* __restrict__ Woh) {
  size_t i = ((size_t)blockIdx.x * 256 + threadIdx.x) * 8;
  const float* src; _Float16* dst; size_t off;
  if (i < 4194304u)      { src = X;  dst = Xh;              off = i; }
  else if (i < 5242880u) { src = Wq; dst = Wqkvh;           off = i - 4194304u; }
  else if (i < 6291456u) { src = Wk; dst = Wqkvh + 1048576; off = i - 5242880u; }
  else if (i < 7340032u) { src = Wv; dst = Wqkvh + 2097152; off = i - 6291456u; }
  else                   { src = Wo; dst = Woh;             off = i - 7340032u; }
  *(f16x8*)(dst + off) = cvt8(src + off);
}

// ---- QKV GEMM: C[4096,3072] = Xh @ W^T (unchanged from R5/R7) -------------
template <int BH>
__global__ __launch_bounds__(256) void gemm_qkv(
    const _Float16* __restrict__ Xh, const float* __restrict__ Wq,
    const float* __restrict__ Wk, const float* __restrict__ Wv,
    const _Float16* __restrict__ Wh, _Float16* __restrict__ Qh,
    _Float16* __restrict__ Kh, _Float16* __restrict__ Vth) {
  __shared__ _Float16 As[128 * 72];
  __shared__ _Float16 Bs[128 * 72];
  const int tid = threadIdx.x;
  const int wave = tid >> 6, lane = tid & 63;
  const int quad = lane >> 4, l16 = lane & 15;
  const int wm = (wave >> 1) * 64, wn = (wave & 1) * 64;
  const int bn = blockIdx.x, bm = blockIdx.y;    // XCD = bn%8
  const int mat = bn >> 3;                       // 0=Q 1=K 2=V (block-uniform)
  const float* Bsrc = (mat == 0) ? Wq : (mat == 1) ? Wk : Wv;
  const int brow0 = (bn & 7) * 128;

  f32x4 acc[4][4] = {};

  for (int k0 = 0; k0 < 1024; k0 += 64) {
    __syncthreads();
#pragma unroll
    for (int j = 0; j < 4; ++j) {
      int idx = tid + j * 256;
      int row = idx >> 3, c8 = idx & 7;
      *(int4*)&As[row * 72 + c8 * 8] =
          *(const int4*)&Xh[(size_t)(bm * 128 + row) * 1024 + k0 + c8 * 8];
      if (BH)
        *(int4*)&Bs[row * 72 + c8 * 8] =
            *(const int4*)&Wh[(size_t)(bn * 128 + row) * 1024 + k0 + c8 * 8];
      else
        *(f16x8*)&Bs[row * 72 + c8 * 8] =
            cvt8(&Bsrc[(size_t)(brow0 + row) * 1024 + k0 + c8 * 8]);
    }
    __syncthreads();
#pragma unroll
    for (int kc = 0; kc < 2; ++kc) {
      f16x8 af[4], bf[4];
#pragma unroll
      for (int t = 0; t < 4; ++t) {
        af[t] = *(const f16x8*)&As[(wm + t * 16 + l16) * 72 + kc * 32 + quad * 8];
        bf[t] = *(const f16x8*)&Bs[(wn + t * 16 + l16) * 72 + kc * 32 + quad * 8];
      }
#pragma unroll
      for (int mt = 0; mt < 4; ++mt)
#pragma unroll
        for (int nt = 0; nt < 4; ++nt)
          acc[mt][nt] = MFMA16(af[mt], bf[nt], acc[mt][nt]);
    }
  }

#pragma unroll
  for (int mt = 0; mt < 4; ++mt) {
    int m_base = bm * 128 + wm + mt * 16 + quad * 4;
    int b = m_base >> 11, sb = m_base & 2047;
#pragma unroll
    for (int nt = 0; nt < 4; ++nt) {
      int ob = (bn * 128 + wn + nt * 16) & 1023;
      int h = ob >> 6;
      int dh = (ob & 63) + l16;
      size_t bh = (size_t)(b * 16 + h);
      if (mat == 0) {
#pragma unroll
        for (int r = 0; r < 4; ++r)
          Qh[(bh * 2048 + sb + r) * 64 + dh] = (_Float16)(acc[mt][nt][r] * QSCALE);
      } else if (mat == 1) {
#pragma unroll
        for (int r = 0; r < 4; ++r)
          Kh[(bh * 2048 + sb + r) * 64 + dh] = (_Float16)acc[mt][nt][r];
      } else {
        f16x4 pk;
        pk[0] = (_Float16)acc[mt][nt][0];
        pk[1] = (_Float16)acc[mt][nt][1];
        pk[2] = (_Float16)acc[mt][nt][2];
        pk[3] = (_Float16)acc[mt][nt][3];
        *(f16x4*)&Vth[(bh * 64 + dh) * 2048 + sb] = pk;
      }
    }
  }
}

// ---- attention: S^T orientation, in-register P, no Pl --------------------
// 4 waves x 32 q-rows (128/block); grid.x = bh (XCD pin), qt = 15-y.
__global__ __launch_bounds__(256) void attn_kernel(
    const _Float16* __restrict__ Qg, const _Float16* __restrict__ Kg,
    const _Float16* __restrict__ Vtg, _Float16* __restrict__ Og) {
  __shared__ _Float16 Kl[128 * 72];        // [key][dh]   18,432 B
  __shared__ _Float16 Vl[64 * 136];        // [dh][key]   17,408 B (35,840)
  const int bh = blockIdx.x;               // XCD = bh % 8
  const int qt = 15 - (int)blockIdx.y;     // heavy tiles dispatched first
  const int q0 = qt * 128;
  const int tid = threadIdx.x;
  const int wave = tid >> 6, lane = tid & 63;
  const int l31 = lane & 31, hl = lane >> 5;
  const int b = bh >> 4, h = bh & 15;
  const int qrow = q0 + wave * 32 + l31;   // this lane's q row (both hl halves)

  // Q A/B-frag (identical lane map): [row=l31][k = 16t + 8*hl + j]
  const _Float16* Qbase =
      Qg + ((size_t)bh * 2048 + qrow) * 64 + hl * 8;
  f16x8 aq[4];
#pragma unroll
  for (int t = 0; t < 4; ++t) aq[t] = *(const f16x8*)(Qbase + 16 * t);

  f32x16 oacc[2] = {};   // O^T: col = qrow (l31), row-regs = dh
  float lsum = 0.f;      // partial sum over the 64 keys/iter this lane holds

  const int ktiles = qt + 1;
  for (int kt = 0; kt < ktiles; ++kt) {
    const int k0 = kt << 7;
    __syncthreads();
#pragma unroll
    for (int i = tid; i < 1024; i += 256) {     // K tile: 128 keys x 64 dh
      int row = i >> 3, c8 = i & 7;
      *(int4*)&Kl[row * 72 + c8 * 8] =
          *(const int4*)&Kg[((size_t)bh * 2048 + k0 + row) * 64 + c8 * 8];
    }
#pragma unroll
    for (int i = tid; i < 1024; i += 256) {     // V^T tile: 64 dh x 128 keys
      int row = i >> 4, c16 = i & 15;
      *(int4*)&Vl[row * 136 + c16 * 8] =
          *(const int4*)&Vtg[((size_t)bh * 64 + row) * 2048 + k0 + c16 * 8];
    }
    __syncthreads();

    const bool diag = (kt == ktiles - 1);       // k0 == q0 on last tile

#pragma unroll
    for (int s32t = 0; s32t < 4; ++s32t) {
      // T = K*Q^T : C/D col = l31 = qrow, row = key_loc = (r&3)+8(r>>2)+4hl
      f32x16 tv = {};
#pragma unroll
      for (int t = 0; t < 4; ++t) {
        f16x8 kb = *(const f16x8*)&Kl[(s32t * 32 + l31) * 72 + t * 16 + hl * 8];
        tv = MFMA32(kb, aq[t], tv);
      }
      // mask, exp2, lsum, pack pairs (keys (2i),(2i+1) are adjacent)
      int pkx[8];
#pragma unroll
      for (int i = 0; i < 8; ++i) {
        float x0 = tv[2 * i], x1 = tv[2 * i + 1];
        int kg = k0 + s32t * 32 + ((2 * i) & 3) + 8 * (i >> 1) + 4 * hl;
        if (diag) {
          if (kg > qrow) x0 = -1e30f;
          if (kg + 1 > qrow) x1 = -1e30f;
        }
        x0 = __builtin_amdgcn_exp2f(x0);
        x1 = __builtin_amdgcn_exp2f(x1);
        lsum += x0 + x1;
        pkx[i] = __builtin_bit_cast(int, pk2(x0, x1));
      }
      // half-wave exchange: receiver hl=0 wants partner pkx{0,1,4,5};
      // receiver hl=1 wants partner pkx{2,3,6,7}. Sender pre-selects.
      int s0 = hl ? pkx[0] : pkx[2];
      int s1 = hl ? pkx[1] : pkx[3];
      int s2 = hl ? pkx[4] : pkx[6];
      int s3 = hl ? pkx[5] : pkx[7];
      int r0 = __shfl_xor(s0, 32);
      int r1 = __shfl_xor(s1, 32);
      int r2 = __shfl_xor(s2, 32);
      int r3 = __shfl_xor(s3, 32);
      // B-frag kt0 (keys s32t*32 + 0..15): lane k = 8*hl + j
      int4 f0, f1;
      f0.x = hl ? r0 : pkx[0];      // hl0: keys 0,1   hl1: keys 8,9
      f0.y = hl ? r1 : pkx[1];      // hl0: keys 2,3   hl1: keys 10,11
      f0.z = hl ? pkx[2] : r0;      // hl0: keys 4,5   hl1: keys 12,13
      f0.w = hl ? pkx[3] : r1;      // hl0: keys 6,7   hl1: keys 14,15
      // B-frag kt1 (keys s32t*32 + 16..31)
      f1.x = hl ? r2 : pkx[4];
      f1.y = hl ? r3 : pkx[5];
      f1.z = hl ? pkx[6] : r2;
      f1.w = hl ? pkx[7] : r3;
      f16x8 bp0 = __builtin_bit_cast(f16x8, f0);
      f16x8 bp1 = __builtin_bit_cast(f16x8, f1);
      // O^T += V^T * P^T  (A = V^T: m = dh, k = key)
#pragma unroll
      for (int d = 0; d < 2; ++d) {
        f16x8 vb0 = *(const f16x8*)&Vl[(d * 32 + l31) * 136 + s32t * 32 + hl * 8];
        f16x8 vb1 =
            *(const f16x8*)&Vl[(d * 32 + l31) * 136 + s32t * 32 + 16 + hl * 8];
        oacc[d] = MFMA32(vb0, bp0, oacc[d]);
        oacc[d] = MFMA32(vb1, bp1, oacc[d]);
      }
    }
  }

  // total row sum = own half + partner half; write O as f16x4 chunks
  lsum += __shfl_xor(lsum, 32);
  float inv = 1.0f / lsum;
#pragma unroll
  for (int d = 0; d < 2; ++d)
#pragma unroll
    for (int rq = 0; rq < 4; ++rq) {
      f16x4 o;
#pragma unroll
      for (int j = 0; j < 4; ++j)
        o[j] = (_Float16)(oacc[d][rq * 4 + j] * inv);
      int dh = d * 32 + 8 * rq + 4 * hl;   // row map: j + 8*rq + 4*hl
      *(f16x4*)&Og[(((size_t)b * 2048 + qrow) * 16 + h) * 64 + dh] = o;
    }
}

// ---- output GEMM: out = Og(f16) @ Wo^T. 128x64 tiles, 512 blocks ----------
template <int BH>
__global__ __launch_bounds__(256) void gemm_out(
    const _Float16* __restrict__ A, const float* __restrict__ Wo,
    const _Float16* __restrict__ Woh, float* __restrict__ Co) {
  __shared__ _Float16 As[128 * 72];
  __shared__ _Float16 Bs[64 * 72];
  const int tid = threadIdx.x;
  const int wave = tid >> 6, lane = tid & 63;
  const int quad = lane >> 4, l16 = lane & 15;
  const int wm = (wave >> 1) * 64, wn = (wave & 1) * 32;
  const int bn = blockIdx.x, bm = blockIdx.y;   // bn 0..15 (64-col tiles)

  f32x4 acc[4][2] = {};

  for (int k0 = 0; k0 < 1024; k0 += 64) {
    __syncthreads();
#pragma unroll
    for (int j = 0; j < 4; ++j) {
      int idx = tid + j * 256;
      int row = idx >> 3, c8 = idx & 7;
      *(int4*)&As[row * 72 + c8 * 8] =
          *(const int4*)&A[(size_t)(bm * 128 + row) * 1024 + k0 + c8 * 8];
    }
#pragma unroll
    for (int j = 0; j < 2; ++j) {
      int idx = tid + j * 256;
      int row = idx >> 3, c8 = idx & 7;
      if (BH)
        *(int4*)&Bs[row * 72 + c8 * 8] =
            *(const int4*)&Woh[(size_t)(bn * 64 + row) * 1024 + k0 + c8 * 8];
      else
        *(f16x8*)&Bs[row * 72 + c8 * 8] =
            cvt8(&Wo[(size_t)(bn * 64 + row) * 1024 + k0 + c8 * 8]);
    }
    __syncthreads();
#pragma unroll
    for (int kc = 0; kc < 2; ++kc) {
      f16x8 af[4], bf[2];
#pragma unroll
      for (int t = 0; t < 4; ++t)
        af[t] = *(const f16x8*)&As[(wm + t * 16 + l16) * 72 + kc * 32 + quad * 8];
#pragma unroll
      for (int t = 0; t < 2; ++t)
        bf[t] = *(const f16x8*)&Bs[(wn + t * 16 + l16) * 72 + kc * 32 + quad * 8];
#pragma unroll
      for (int mt = 0; mt < 4; ++mt)
#pragma unroll
        for (int nt = 0; nt < 2; ++nt)
          acc[mt][nt] = MFMA16(af[mt], bf[nt], acc[mt][nt]);
    }
  }

#pragma unroll
  for (int mt = 0; mt < 4; ++mt) {
    int m_base = bm * 128 + wm + mt * 16 + quad * 4;
#pragma unroll
    for (int nt = 0; nt < 2; ++nt) {
      int n = bn * 64 + wn + nt * 16 + l16;
#pragma unroll
      for (int r = 0; r < 4; ++r)
        Co[(size_t)(m_base + r) * 1024 + n] = acc[mt][nt][r];
    }
  }
}

extern "C" void kernel_launch(void* const* d_in, const int* in_sizes, int n_in,
                              void* d_out, int out_size, void* d_ws, size_t ws_size,
                              hipStream_t stream) {
  const float* X  = (const float*)d_in[0];
  const float* Wq = (const float*)d_in[1];
  const float* Wk = (const float*)d_in[2];
  const float* Wv = (const float*)d_in[3];
  const float* Wo = (const float*)d_in[4];
  float* out = (float*)d_out;

  _Float16* Qh    = (_Float16*)d_out;        // 4M halves (d_out scratch)
  _Float16* Kh    = Qh + 4194304;            // 4M halves
  _Float16* Vth   = (_Float16*)d_ws;         // 4M halves [b,h,dh,s]
  _Float16* Xh    = Vth + 4194304;           // 4M halves (Og overlay)
  _Float16* Og    = Xh;
  _Float16* Wqkvh = Xh + 4194304;            // 3M halves (big path only)
  _Float16* Woh   = Wqkvh + 3145728;         // 1M halves

  const bool big = (ws_size >= 25165824u);

  convert_all<<<big ? 4096 : 2048, 256, 0, stream>>>(X, Wq, Wk, Wv, Wo,
                                                     Xh, Wqkvh, Woh);
  if (big)
    gemm_qkv<1><<<dim3(24, 32), 256, 0, stream>>>(Xh, Wq, Wk, Wv, Wqkvh,
                                                  Qh, Kh, Vth);
  else
    gemm_qkv<0><<<dim3(24, 32), 256, 0, stream>>>(Xh, Wq, Wk, Wv, nullptr,
                                                  Qh, Kh, Vth);
  attn_kernel<<<dim3(32, 16), 256, 0, stream>>>(Qh, Kh, Vth, Og);
  if (big)
    gemm_out<1><<<dim3(16, 32), 256, 0, stream>>>(Og, Wo, Woh, out);
  else
    gemm_out<0><<<dim3(16, 32), 256, 0, stream>>>(Og, Wo, nullptr, out);
}

// Round 9
// 184.249 us; speedup vs baseline: 1.4511x; 1.1533x over previous
//
#include <hip/hip_runtime.h>
#include <math.h>

// ---------------------------------------------------------------------------
// Attn_14920716386547 R9.
// R8: 212.5 us; attn 74 us UNCHANGED after deleting P round-trip -> P was
// never the critical path. Attn is latency-bound at 2 waves/SIMD (65% stall,
// grid 512 = 2 blk/CU, MFMA ~9%). Fix: in-block K-parallelism.
//  * attn: 512-thread blocks, two 4-wave groups; group g handles ktiles
//    kt%2==g in its own K/V LDS (71.7 KB, still 2 blk/CU) -> 4 waves/SIMD.
//    Fixed-max softmax is associative -> groups keep private O/lsum partials,
//    merged once via LDS (stride-33 f32, conflict-free). Barriers halve.
//  * everything else identical to R8.
// ws (halves): Vth [0,4M) | Xh/Og overlay [4M,8M) | Wqkvh [8M,11M) |
//   Woh [11M,12M) (big path only). d_out: Qh|Kh scratch (dead before out).
// ---------------------------------------------------------------------------

typedef _Float16 f16x8 __attribute__((ext_vector_type(8)));
typedef _Float16 f16x4 __attribute__((ext_vector_type(4)));
typedef _Float16 f16x2 __attribute__((ext_vector_type(2)));
typedef __attribute__((ext_vector_type(4))) float f32x4;
typedef __attribute__((ext_vector_type(16))) float f32x16;

#define MFMA16(a, b, c) __builtin_amdgcn_mfma_f32_16x16x32_f16(a, b, c, 0, 0, 0)
#define MFMA32(a, b, c) __builtin_amdgcn_mfma_f32_32x32x16_f16(a, b, c, 0, 0, 0)
#define QSCALE 0.18033688f /* 0.125 * log2(e): attention runs in exp2 domain */

__device__ __forceinline__ f16x2 pk2(float x, float y) {
  return __builtin_bit_cast(f16x2, __builtin_amdgcn_cvt_pkrtz(x, y));
}

__device__ __forceinline__ f16x8 cvt8(const float* __restrict__ p) {
  float4 a = *(const float4*)p;
  float4 b = *(const float4*)(p + 4);
  f16x2 p0 = pk2(a.x, a.y), p1 = pk2(a.z, a.w);
  f16x2 p2 = pk2(b.x, b.y), p3 = pk2(b.z, b.w);
  f16x8 h;
  h[0] = p0[0]; h[1] = p0[1]; h[2] = p1[0]; h[3] = p1[1];
  h[4] = p2[0]; h[5] = p2[1]; h[6] = p3[0]; h[7] = p3[1];
  return h;
}

// ---- fp32 -> fp16 convert: X always; with grid=4096 also Wq|Wk|Wv|Wo ------
__global__ void convert_all(const float* __restrict__ X, const float* __restrict__ Wq,
                            const float* __restrict__ Wk, const float* __restrict__ Wv,
                            const float* __restrict__ Wo, _Float16* __restrict__ Xh,
                            _Float16* __restrict__ Wqkvh, _Float16* __restrict__ Woh) {
  size_t i = ((size_t)blockIdx.x * 256 + threadIdx.x) * 8;
  const float* src; _Float16* dst; size_t off;
  if (i < 4194304u)      { src = X;  dst = Xh;              off = i; }
  else if (i < 5242880u) { src = Wq; dst = Wqkvh;           off = i - 4194304u; }
  else if (i < 6291456u) { src = Wk; dst = Wqkvh + 1048576; off = i - 5242880u; }
  else if (i < 7340032u) { src = Wv; dst = Wqkvh + 2097152; off = i - 6291456u; }
  else                   { src = Wo; dst = Woh;             off = i - 7340032u; }
  *(f16x8*)(dst + off) = cvt8(src + off);
}

// ---- QKV GEMM: C[4096,3072] = Xh @ W^T (unchanged from R5) ---------------
template <int BH>
__global__ __launch_bounds__(256) void gemm_qkv(
    const _Float16* __restrict__ Xh, const float* __restrict__ Wq,
    const float* __restrict__ Wk, const float* __restrict__ Wv,
    const _Float16* __restrict__ Wh, _Float16* __restrict__ Qh,
    _Float16* __restrict__ Kh, _Float16* __restrict__ Vth) {
  __shared__ _Float16 As[128 * 72];
  __shared__ _Float16 Bs[128 * 72];
  const int tid = threadIdx.x;
  const int wave = tid >> 6, lane = tid & 63;
  const int quad = lane >> 4, l16 = lane & 15;
  const int wm = (wave >> 1) * 64, wn = (wave & 1) * 64;
  const int bn = blockIdx.x, bm = blockIdx.y;    // XCD = bn%8
  const int mat = bn >> 3;                       // 0=Q 1=K 2=V (block-uniform)
  const float* Bsrc = (mat == 0) ? Wq : (mat == 1) ? Wk : Wv;
  const int brow0 = (bn & 7) * 128;

  f32x4 acc[4][4] = {};

  for (int k0 = 0; k0 < 1024; k0 += 64) {
    __syncthreads();
#pragma unroll
    for (int j = 0; j < 4; ++j) {
      int idx = tid + j * 256;
      int row = idx >> 3, c8 = idx & 7;
      *(int4*)&As[row * 72 + c8 * 8] =
          *(const int4*)&Xh[(size_t)(bm * 128 + row) * 1024 + k0 + c8 * 8];
      if (BH)
        *(int4*)&Bs[row * 72 + c8 * 8] =
            *(const int4*)&Wh[(size_t)(bn * 128 + row) * 1024 + k0 + c8 * 8];
      else
        *(f16x8*)&Bs[row * 72 + c8 * 8] =
            cvt8(&Bsrc[(size_t)(brow0 + row) * 1024 + k0 + c8 * 8]);
    }
    __syncthreads();
#pragma unroll
    for (int kc = 0; kc < 2; ++kc) {
      f16x8 af[4], bf[4];
#pragma unroll
      for (int t = 0; t < 4; ++t) {
        af[t] = *(const f16x8*)&As[(wm + t * 16 + l16) * 72 + kc * 32 + quad * 8];
        bf[t] = *(const f16x8*)&Bs[(wn + t * 16 + l16) * 72 + kc * 32 + quad * 8];
      }
#pragma unroll
      for (int mt = 0; mt < 4; ++mt)
#pragma unroll
        for (int nt = 0; nt < 4; ++nt)
          acc[mt][nt] = MFMA16(af[mt], bf[nt], acc[mt][nt]);
    }
  }

#pragma unroll
  for (int mt = 0; mt < 4; ++mt) {
    int m_base = bm * 128 + wm + mt * 16 + quad * 4;
    int b = m_base >> 11, sb = m_base & 2047;
#pragma unroll
    for (int nt = 0; nt < 4; ++nt) {
      int ob = (bn * 128 + wn + nt * 16) & 1023;
      int h = ob >> 6;
      int dh = (ob & 63) + l16;
      size_t bh = (size_t)(b * 16 + h);
      if (mat == 0) {
#pragma unroll
        for (int r = 0; r < 4; ++r)
          Qh[(bh * 2048 + sb + r) * 64 + dh] = (_Float16)(acc[mt][nt][r] * QSCALE);
      } else if (mat == 1) {
#pragma unroll
        for (int r = 0; r < 4; ++r)
          Kh[(bh * 2048 + sb + r) * 64 + dh] = (_Float16)acc[mt][nt][r];
      } else {
        f16x4 pk;
        pk[0] = (_Float16)acc[mt][nt][0];
        pk[1] = (_Float16)acc[mt][nt][1];
        pk[2] = (_Float16)acc[mt][nt][2];
        pk[3] = (_Float16)acc[mt][nt][3];
        *(f16x4*)&Vth[(bh * 64 + dh) * 2048 + sb] = pk;
      }
    }
  }
}

// ---- attention R9: 512 threads, 2 groups x 4 waves, group g takes kt%2==g -
// S^T = K*Q^T in-register P (R8 math); private O/lsum partials, LDS merge.
__global__ __launch_bounds__(512) void attn_kernel(
    const _Float16* __restrict__ Qg, const _Float16* __restrict__ Kg,
    const _Float16* __restrict__ Vtg, _Float16* __restrict__ Og) {
  __shared__ _Float16 smem[2 * (128 * 72 + 64 * 136)];   // 71,680 B
  const int bh = blockIdx.x;               // XCD = bh % 8
  const int qt = 15 - (int)blockIdx.y;     // heavy tiles dispatched first
  const int q0 = qt * 128;
  const int tid = threadIdx.x;
  const int group = tid >> 8;              // 0/1: even/odd ktiles
  const int tidg = tid & 255;
  const int wv = (tid >> 6) & 3;           // wave within group
  const int lane = tid & 63;
  const int l31 = lane & 31, hl = lane >> 5;
  const int b = bh >> 4, h = bh & 15;
  const int qrow = q0 + wv * 32 + l31;     // this lane's q row

  _Float16* Kl = smem + group * (128 * 72 + 64 * 136);   // [key][dh]
  _Float16* Vl = Kl + 128 * 72;                          // [dh][key]

  // Q A/B-frag (identical lane map): [row=l31][k = 16t + 8*hl + j]
  const _Float16* Qbase = Qg + ((size_t)bh * 2048 + qrow) * 64 + hl * 8;
  f16x8 aq[4];
#pragma unroll
  for (int t = 0; t < 4; ++t) aq[t] = *(const f16x8*)(Qbase + 16 * t);

  f32x16 oacc[2] = {};   // O^T partial: col = qrow (l31), row-regs = dh
  float lsum = 0.f;

  const int nmax = (qt + 2) >> 1;          // group 0 iter count (>= group 1)
  for (int it = 0; it < nmax; ++it) {
    const int kt = 2 * it + group;
    const bool valid = (kt <= qt);
    const int k0 = kt << 7;
    __syncthreads();
    if (valid) {
#pragma unroll
      for (int i = tidg; i < 1024; i += 256) {  // K tile: 128 keys x 64 dh
        int row = i >> 3, c8 = i & 7;
        *(int4*)&Kl[row * 72 + c8 * 8] =
            *(const int4*)&Kg[((size_t)bh * 2048 + k0 + row) * 64 + c8 * 8];
      }
#pragma unroll
      for (int i = tidg; i < 1024; i += 256) {  // V^T tile: 64 dh x 128 keys
        int row = i >> 4, c16 = i & 15;
        *(int4*)&Vl[row * 136 + c16 * 8] =
            *(const int4*)&Vtg[((size_t)bh * 64 + row) * 2048 + k0 + c16 * 8];
      }
    }
    __syncthreads();
    if (!valid) continue;

    const bool diag = (kt == qt);

#pragma unroll
    for (int s32t = 0; s32t < 4; ++s32t) {
      // T = K*Q^T : C/D col = l31 = qrow, row = key_loc = (r&3)+8(r>>2)+4hl
      f32x16 tv = {};
#pragma unroll
      for (int t = 0; t < 4; ++t) {
        f16x8 kb = *(const f16x8*)&Kl[(s32t * 32 + l31) * 72 + t * 16 + hl * 8];
        tv = MFMA32(kb, aq[t], tv);
      }
      // mask, exp2, lsum, pack adjacent key pairs
      int pkx[8];
#pragma unroll
      for (int i = 0; i < 8; ++i) {
        float x0 = tv[2 * i], x1 = tv[2 * i + 1];
        int kg = k0 + s32t * 32 + ((2 * i) & 3) + 8 * (i >> 1) + 4 * hl;
        if (diag) {
          if (kg > qrow) x0 = -1e30f;
          if (kg + 1 > qrow) x1 = -1e30f;
        }
        x0 = __builtin_amdgcn_exp2f(x0);
        x1 = __builtin_amdgcn_exp2f(x1);
        lsum += x0 + x1;
        pkx[i] = __builtin_bit_cast(int, pk2(x0, x1));
      }
      // half-wave exchange (R8-verified routing)
      int s0 = hl ? pkx[0] : pkx[2];
      int s1 = hl ? pkx[1] : pkx[3];
      int s2 = hl ? pkx[4] : pkx[6];
      int s3 = hl ? pkx[5] : pkx[7];
      int r0 = __shfl_xor(s0, 32);
      int r1 = __shfl_xor(s1, 32);
      int r2 = __shfl_xor(s2, 32);
      int r3 = __shfl_xor(s3, 32);
      int4 f0, f1;
      f0.x = hl ? r0 : pkx[0];
      f0.y = hl ? r1 : pkx[1];
      f0.z = hl ? pkx[2] : r0;
      f0.w = hl ? pkx[3] : r1;
      f1.x = hl ? r2 : pkx[4];
      f1.y = hl ? r3 : pkx[5];
      f1.z = hl ? pkx[6] : r2;
      f1.w = hl ? pkx[7] : r3;
      f16x8 bp0 = __builtin_bit_cast(f16x8, f0);
      f16x8 bp1 = __builtin_bit_cast(f16x8, f1);
      // O^T += V^T * P^T
#pragma unroll
      for (int d = 0; d < 2; ++d) {
        f16x8 vb0 = *(const f16x8*)&Vl[(d * 32 + l31) * 136 + s32t * 32 + hl * 8];
        f16x8 vb1 =
            *(const f16x8*)&Vl[(d * 32 + l31) * 136 + s32t * 32 + 16 + hl * 8];
        oacc[d] = MFMA32(vb0, bp0, oacc[d]);
        oacc[d] = MFMA32(vb1, bp1, oacc[d]);
      }
    }
  }

  // merge group 1 partials into group 0 via LDS (group 1's K/V region dead)
  __syncthreads();
  float* mbuf = (float*)(smem + (128 * 72 + 64 * 136));
  float* slot = mbuf + (wv * 64 + lane) * 33;   // stride 33 -> conflict-free
  if (group == 1) {
#pragma unroll
    for (int d = 0; d < 2; ++d)
#pragma unroll
      for (int j = 0; j < 16; ++j) slot[d * 16 + j] = oacc[d][j];
    slot[32] = lsum;
  }
  __syncthreads();
  if (group == 0) {
#pragma unroll
    for (int d = 0; d < 2; ++d)
#pragma unroll
      for (int j = 0; j < 16; ++j) oacc[d][j] += slot[d * 16 + j];
    lsum += slot[32];
    lsum += __shfl_xor(lsum, 32);
    float inv = 1.0f / lsum;
#pragma unroll
    for (int d = 0; d < 2; ++d)
#pragma unroll
      for (int rq = 0; rq < 4; ++rq) {
        f16x4 o;
#pragma unroll
        for (int j = 0; j < 4; ++j)
          o[j] = (_Float16)(oacc[d][rq * 4 + j] * inv);
        int dh = d * 32 + 8 * rq + 4 * hl;
        *(f16x4*)&Og[(((size_t)b * 2048 + qrow) * 16 + h) * 64 + dh] = o;
      }
  }
}

// ---- output GEMM: out = Og(f16) @ Wo^T. 128x64 tiles, 512 blocks ----------
template <int BH>
__global__ __launch_bounds__(256) void gemm_out(
    const _Float16* __restrict__ A, const float* __restrict__ Wo,
    const _Float16* __restrict__ Woh, float* __restrict__ Co) {
  __shared__ _Float16 As[128 * 72];
  __shared__ _Float16 Bs[64 * 72];
  const int tid = threadIdx.x;
  const int wave = tid >> 6, lane = tid & 63;
  const int quad = lane >> 4, l16 = lane & 15;
  const int wm = (wave >> 1) * 64, wn = (wave & 1) * 32;
  const int bn = blockIdx.x, bm = blockIdx.y;

  f32x4 acc[4][2] = {};

  for (int k0 = 0; k0 < 1024; k0 += 64) {
    __syncthreads();
#pragma unroll
    for (int j = 0; j < 4; ++j) {
      int idx = tid + j * 256;
      int row = idx >> 3, c8 = idx & 7;
      *(int4*)&As[row * 72 + c8 * 8] =
          *(const int4*)&A[(size_t)(bm * 128 + row) * 1024 + k0 + c8 * 8];
    }
#pragma unroll
    for (int j = 0; j < 2; ++j) {
      int idx = tid + j * 256;
      int row = idx >> 3, c8 = idx & 7;
      if (BH)
        *(int4*)&Bs[row * 72 + c8 * 8] =
            *(const int4*)&Woh[(size_t)(bn * 64 + row) * 1024 + k0 + c8 * 8];
      else
        *(f16x8*)&Bs[row * 72 + c8 * 8] =
            cvt8(&Wo[(size_t)(bn * 64 + row) * 1024 + k0 + c8 * 8]);
    }
    __syncthreads();
#pragma unroll
    for (int kc = 0; kc < 2; ++kc) {
      f16x8 af[4], bf[2];
#pragma unroll
      for (int t = 0; t < 4; ++t)
        af[t] = *(const f16x8*)&As[(wm + t * 16 + l16) * 72 + kc * 32 + quad * 8];
#pragma unroll
      for (int t = 0; t < 2; ++t)
        bf[t] = *(const f16x8*)&Bs[(wn + t * 16 + l16) * 72 + kc * 32 + quad * 8];
#pragma unroll
      for (int mt = 0; mt < 4; ++mt)
#pragma unroll
        for (int nt = 0; nt < 2; ++nt)
          acc[mt][nt] = MFMA16(af[mt], bf[nt], acc[mt][nt]);
    }
  }

#pragma unroll
  for (int mt = 0; mt < 4; ++mt) {
    int m_base = bm * 128 + wm + mt * 16 + quad * 4;
#pragma unroll
    for (int nt = 0; nt < 2; ++nt) {
      int n = bn * 64 + wn + nt * 16 + l16;
#pragma unroll
      for (int r = 0; r < 4; ++r)
        Co[(size_t)(m_base + r) * 1024 + n] = acc[mt][nt][r];
    }
  }
}

extern "C" void kernel_launch(void* const* d_in, const int* in_sizes, int n_in,
                              void* d_out, int out_size, void* d_ws, size_t ws_size,
                              hipStream_t stream) {
  const float* X  = (const float*)d_in[0];
  const float* Wq = (const float*)d_in[1];
  const float* Wk = (const float*)d_in[2];
  const float* Wv = (const float*)d_in[3];
  const float* Wo = (const float*)d_in[4];
  float* out = (float*)d_out;

  _Float16* Qh    = (_Float16*)d_out;        // 4M halves (d_out scratch)
  _Float16* Kh    = Qh + 4194304;            // 4M halves
  _Float16* Vth   = (_Float16*)d_ws;         // 4M halves [b,h,dh,s]
  _Float16* Xh    = Vth + 4194304;           // 4M halves (Og overlay)
  _Float16* Og    = Xh;
  _Float16* Wqkvh = Xh + 4194304;            // 3M halves (big path only)
  _Float16* Woh   = Wqkvh + 3145728;         // 1M halves

  const bool big = (ws_size >= 25165824u);

  convert_all<<<big ? 4096 : 2048, 256, 0, stream>>>(X, Wq, Wk, Wv, Wo,
                                                     Xh, Wqkvh, Woh);
  if (big)
    gemm_qkv<1><<<dim3(24, 32), 256, 0, stream>>>(Xh, Wq, Wk, Wv, Wqkvh,
                                                  Qh, Kh, Vth);
  else
    gemm_qkv<0><<<dim3(24, 32), 256, 0, stream>>>(Xh, Wq, Wk, Wv, nullptr,
                                                  Qh, Kh, Vth);
  attn_kernel<<<dim3(32, 16), 512, 0, stream>>>(Qh, Kh, Vth, Og);
  if (big)
    gemm_out<1><<<dim3(16, 32), 256, 0, stream>>>(Og, Wo, Woh, out);
  else
    gemm_out<0><<<dim3(16, 32), 256, 0, stream>>>(Og, Wo, nullptr, out);
}